// Round 6
// baseline (142.144 us; speedup 1.0000x reference)
//
#include <hip/hip_runtime.h>

// Problem constants (from reference)
constexpr int   NB         = 128;          // bins per axis
constexpr int   NCELL      = NB * NB;      // 16384 cells = 64 KB fp32
constexpr float S          = 7.8125f;      // 1000/128, exact in fp32
constexpr int   NUM_NETS   = 100000;
constexpr int   NUM_NODES  = 200000;
constexpr int   NUM_MOVABLE= 180000;
constexpr int   NUM_PINS   = 400000;
constexpr float UNIT_H_CAP = 1.5f;
constexpr float UNIT_V_CAP = 1.4f;

#define TPB    512   // 256 blocks x 512 = 131072 threads >= 100000 nets: 1 net/thread
#define NDB    256   // one block per CU: LDS atomic pipe fully spread
#define NPAR   8     // parity groups (XCD count): reduce block L sums b == L (mod 8)

__device__ __forceinline__ float edgef(int t) { return (float)t * S; }

// exact bin index: edge(a) <= v < edge(a+1)
__device__ __forceinline__ int bin_of(float v) {
    int t = (int)floorf(v / S);
    while (edgef(t + 1) <= v) ++t;
    while (edgef(t)     >  v) --t;
    return t;
}

__device__ __forceinline__ float phi(int t, float lo, float hi) {
    return fminf(fmaxf(edgef(t), lo), hi);
}

// second difference of the clamp-ramp: <=4 nonzeros (indices >=128 are dropped
// by the caller; they never influence bins 0..127).
__device__ __forceinline__ int second_diff(float lo, float hi,
                                           int* idx, float* val) {
    int a = bin_of(lo);
    int b = bin_of(hi);
    int n = 0;
    idx[n] = a;
    val[n] = phi(a + 1, lo, hi) - 2.f * phi(a, lo, hi) + phi(a - 1, lo, hi);
    ++n;
    idx[n] = a + 1;
    val[n] = phi(a + 2, lo, hi) - 2.f * phi(a + 1, lo, hi) + phi(a, lo, hi);
    ++n;
    if (b > a + 1) {
        idx[n] = b;
        val[n] = phi(b + 1, lo, hi) - 2.f * phi(b, lo, hi) + phi(b - 1, lo, hi);
        ++n;
    }
    if (b > a) {
        idx[n] = b + 1;
        val[n] = phi(b + 2, lo, hi) - 2.f * phi(b + 1, lo, hi) + phi(b, lo, hi);
        ++n;
    }
    return n;
}

// K1: fused bbox gather + LDS-private 2D diff scatter (two phases: x-map,
// y-map). One net per thread. LDS-atomic-pipe bound: ~12.5k lane-ops/block
// at ~4 cyc/lane => ~21 us floor at 256 blocks.
__global__ __launch_bounds__(TPB) void net_diff_kernel(
    const float* __restrict__ pin_pos,
    const float* __restrict__ net_weights,
    const int*   __restrict__ nps,
    const int*   __restrict__ fnp,
    float* __restrict__ Px, float* __restrict__ Py) {
    __shared__ float D[NCELL];   // 64 KB private diff array
    const int tid = threadIdx.x;
    const int n   = blockIdx.x * TPB + tid;
    const bool have = (n < NUM_NETS);

    // Issue all gather loads first so the LDS zero-init overlaps their latency.
    float x0=0,x1=0,x2=0,x3=0,y0=0,y1=0,y2=0,y3=0,w=0;
    int s = 0, e = 0;
    bool fast = false;
    if (have) {
        s = nps[n]; e = nps[n + 1];
        fast = (e - s == 4) && ((s & 3) == 0);
        if (fast) {
            int4 p4 = *(const int4*)(fnp + s);
            x0 = pin_pos[p4.x]; y0 = pin_pos[p4.x + NUM_PINS];
            x1 = pin_pos[p4.y]; y1 = pin_pos[p4.y + NUM_PINS];
            x2 = pin_pos[p4.z]; y2 = pin_pos[p4.z + NUM_PINS];
            x3 = pin_pos[p4.w]; y3 = pin_pos[p4.w + NUM_PINS];
            w  = net_weights[n];
        }
    }

    float4* D4 = (float4*)D;
    for (int i = tid; i < NCELL / 4; i += TPB) D4[i] = make_float4(0,0,0,0);

    float cx = 0.f, cy = 0.f;
    int ixs[4], iys[4];
    float vxs[4], vys[4];
    int nx = 0, ny = 0;

    if (have) {
        float xmin, xmax, ymin, ymax;
        if (fast) {
            xmin = fminf(fminf(x0, x1), fminf(x2, x3));
            xmax = fmaxf(fmaxf(x0, x1), fmaxf(x2, x3));
            ymin = fminf(fminf(y0, y1), fminf(y2, y3));
            ymax = fmaxf(fmaxf(y0, y1), fmaxf(y2, y3));
        } else {
            xmin = 1e30f; xmax = -1e30f; ymin = 1e30f; ymax = -1e30f;
            for (int p = s; p < e; ++p) {
                int pin = fnp[p];
                float px = pin_pos[pin];
                float py = pin_pos[pin + NUM_PINS];
                xmin = fminf(xmin, px); xmax = fmaxf(xmax, px);
                ymin = fminf(ymin, py); ymax = fmaxf(ymax, py);
            }
            if (e > s) w = net_weights[n];
        }
        if (e > s) {
            float dx = xmax - xmin, dy = ymax - ymin;
            cx = (dy > 0.f) ? w / dy : 0.f;
            cy = (dx > 0.f) ? w / dx : 0.f;
            if (cx != 0.f || cy != 0.f) {
                nx = second_diff(xmin, xmax, ixs, vxs);
                ny = second_diff(ymin, ymax, iys, vys);
            }
        }
    }
    __syncthreads();

    // phase 0: x-map (coefficient cx)
    if (have && cx != 0.f) {
        for (int i = 0; i < nx; ++i) {
            int row = ixs[i];
            float cfi = cx * vxs[i];
            if (cfi == 0.f || row >= NB) continue;
            for (int j = 0; j < ny; ++j) {
                int col = iys[j];
                float t = cfi * vys[j];
                if (t == 0.f || col >= NB) continue;
                atomicAdd(&D[row * NB + col], t);   // ds_add_f32, no return
            }
        }
    }
    __syncthreads();
    {
        float4* P = (float4*)(Px + (size_t)blockIdx.x * NCELL);
        for (int i = tid; i < NCELL / 4; i += TPB) {
            P[i] = D4[i];
            D4[i] = make_float4(0,0,0,0);
        }
    }
    __syncthreads();

    // phase 1: y-map (coefficient cy)
    if (have && cy != 0.f) {
        for (int i = 0; i < nx; ++i) {
            int row = ixs[i];
            float cfi = cy * vxs[i];
            if (cfi == 0.f || row >= NB) continue;
            for (int j = 0; j < ny; ++j) {
                int col = iys[j];
                float t = cfi * vys[j];
                if (t == 0.f || col >= NB) continue;
                atomicAdd(&D[row * NB + col], t);
            }
        }
    }
    __syncthreads();
    {
        float4* P = (float4*)(Py + (size_t)blockIdx.x * NCELL);
        for (int i = tid; i < NCELL / 4; i += TPB) P[i] = D4[i];
    }
}

// K2: parity-matched partial reduction. Block L (0..255): parity p = L&7,
// slice s = L>>3. Sums partials b = p, p+8, ... (written by net_diff blocks
// with the same blockIdx%8 -> same XCD under round-robin placement -> the
// writeback lines are L2-local). R[p] holds 8 parity-partial map pairs.
__global__ __launch_bounds__(256) void reduce_kernel(
    const float4* __restrict__ Px, const float4* __restrict__ Py,
    float4* __restrict__ R, int B) {
    constexpr int NC4 = NCELL / 4;          // 4096
    int L = blockIdx.x;
    int p = L & (NPAR - 1);
    int sl = L >> 3;                         // 0..31
    int g = sl * 256 + threadIdx.x;          // 0..8191 (2 maps x 4096)
    int m  = (g < NC4) ? 0 : 1;
    int c4 = g & (NC4 - 1);
    const float4* P = m ? Py : Px;
    float4 a0 = {0,0,0,0}, a1 = {0,0,0,0}, a2 = {0,0,0,0}, a3 = {0,0,0,0};
    int b = p;
    for (; b + 3 * NPAR < B; b += 4 * NPAR) {
        float4 v0 = P[(size_t)b * NC4 + c4];
        float4 v1 = P[(size_t)(b + NPAR) * NC4 + c4];
        float4 v2 = P[(size_t)(b + 2 * NPAR) * NC4 + c4];
        float4 v3 = P[(size_t)(b + 3 * NPAR) * NC4 + c4];
        a0.x += v0.x; a0.y += v0.y; a0.z += v0.z; a0.w += v0.w;
        a1.x += v1.x; a1.y += v1.y; a1.z += v1.z; a1.w += v1.w;
        a2.x += v2.x; a2.y += v2.y; a2.z += v2.z; a2.w += v2.w;
        a3.x += v3.x; a3.y += v3.y; a3.z += v3.z; a3.w += v3.w;
    }
    for (; b < B; b += NPAR) {
        float4 v = P[(size_t)b * NC4 + c4];
        a0.x += v.x; a0.y += v.y; a0.z += v.z; a0.w += v.w;
    }
    float4 r;
    r.x = (a0.x + a1.x) + (a2.x + a3.x);
    r.y = (a0.y + a1.y) + (a2.y + a3.y);
    r.z = (a0.z + a1.z) + (a2.z + a3.z);
    r.w = (a0.w + a1.w) + (a2.w + a3.w);
    R[(size_t)p * (2 * NC4) + g] = r;
}

// K3: single-block fused finish: sum 8 parity maps + x-prefix into Xp,
// barrier, y-prefix + clip -> util.
__global__ __launch_bounds__(256) void finish_kernel(
    const float* __restrict__ R,     // [NPAR][2][NCELL]
    float* __restrict__ Xp,          // [2][NCELL] scratch
    float* __restrict__ util) {
    int t = threadIdx.x;
    int m   = (t >= NB) ? 1 : 0;
    int col = t & (NB - 1);
    const float* Ra = R + (size_t)m * NCELL;
    float* O = Xp + (size_t)m * NCELL;
    float acc = 0.f;
    #pragma unroll 4
    for (int i = 0; i < NB; ++i) {
        int idx = i * NB + col;
        float v = 0.f;
        #pragma unroll
        for (int p = 0; p < NPAR; ++p)
            v += Ra[(size_t)p * (2 * NCELL) + idx];
        acc += v;
        O[idx] = acc;
    }
    __syncthreads();
    if (t < NB) {
        constexpr float invx = 1.f / (S * S * UNIT_H_CAP);
        constexpr float invy = 1.f / (S * S * UNIT_V_CAP);
        const float* Xx = Xp;
        const float* Xy = Xp + NCELL;
        float ax = 0.f, ay = 0.f;
        #pragma unroll 8
        for (int j = 0; j < NB; ++j) {
            int idx = t * NB + j;
            ax += Xx[idx];
            ay += Xy[idx];
            float u = fmaxf(ax * invx, ay * invy);
            util[idx] = fminf(fmaxf(u, 0.5f), 2.0f);
        }
    }
}

// K4: per-movable-node area = sum over <=3x3 bins of ox*util*oy
__global__ __launch_bounds__(256) void node_kernel(
    const float* __restrict__ pos,
    const float* __restrict__ nsx,
    const float* __restrict__ nsy,
    const float* __restrict__ util,
    float* __restrict__ out) {
    int m = blockIdx.x * blockDim.x + threadIdx.x;
    if (m >= NUM_MOVABLE) return;
    float x  = pos[m];
    float y  = pos[NUM_NODES + m];
    float xh = x + nsx[m];
    float yh = y + nsy[m];
    int ax = max(0,      (int)floorf(x  / S) - 1);
    int bx = min(NB - 1, (int)floorf(xh / S) + 1);
    int ay = max(0,      (int)floorf(y  / S) - 1);
    int by = min(NB - 1, (int)floorf(yh / S) + 1);
    float acc = 0.f;
    for (int i = ax; i <= bx; ++i) {
        float ov = fminf(edgef(i + 1), xh) - fmaxf(edgef(i), x);
        if (ov <= 0.f) continue;
        float inner = 0.f;
        for (int j = ay; j <= by; ++j) {
            float ovy = fminf(edgef(j + 1), yh) - fmaxf(edgef(j), y);
            if (ovy > 0.f) inner += ovy * util[i * NB + j];
        }
        acc += ov * inner;
    }
    out[m] = acc;
}

extern "C" void kernel_launch(void* const* d_in, const int* in_sizes, int n_in,
                              void* d_out, int out_size, void* d_ws, size_t ws_size,
                              hipStream_t stream) {
    const float* pos      = (const float*)d_in[0];
    const float* pin_pos  = (const float*)d_in[1];
    const float* nsx      = (const float*)d_in[2];
    const float* nsy      = (const float*)d_in[3];
    const float* nw       = (const float*)d_in[4];
    const int*   npstart  = (const int*)d_in[5];
    const int*   fnp      = (const int*)d_in[6];
    float*       out      = (float*)d_out;

    // ws layout (floats): R[NPAR*2*NCELL] Xp[2*NCELL] util[NCELL]
    //                     Px[B*NCELL] Py[B*NCELL]
    float* w    = (float*)d_ws;
    float* R    = w;                       w += NPAR * 2 * NCELL;
    float* Xp   = w;                       w += 2 * NCELL;
    float* util = w;                       w += NCELL;
    float* Px   = w;

    size_t fixed = (size_t)(w - (float*)d_ws) * sizeof(float);
    int B = NDB;
    if (ws_size > fixed) {
        size_t fit = (ws_size - fixed) / ((size_t)2 * NCELL * sizeof(float));
        if ((size_t)B > fit) B = (int)fit;
    } else {
        B = 1;
    }
    if (B < 1) B = 1;
    float* Py = Px + (size_t)B * NCELL;

    net_diff_kernel<<<B, TPB, 0, stream>>>(pin_pos, nw, npstart, fnp, Px, Py);
    reduce_kernel<<<NDB, 256, 0, stream>>>(
        (const float4*)Px, (const float4*)Py, (float4*)R, B);
    finish_kernel<<<1, 256, 0, stream>>>(R, Xp, util);
    node_kernel<<<(NUM_MOVABLE + 255) / 256, 256, 0, stream>>>(
        pos, nsx, nsy, util, out);
}